// Round 1
// baseline (1493.405 us; speedup 1.0000x reference)
//
#include <hip/hip_runtime.h>

#define NUM_K   4096
#define CDIM    64
#define HWDIM   4096            // 64*64
#define NVEC    65536           // 16 * 64 * 64
#define CHW     (CDIM * HWDIM)  // 262144

// ---- output layout (floats, concatenated in reference return order) ----
#define O_Q     0               // quantized_ste  [16,64,64,64] = 4194304
#define O_LOSS  4194304         // scalar
#define O_IDX   4194305         // encoding_indices [16,64,64] = 65536 (as float)
#define O_W     4259841         // new_weight   [4096,64] = 262144
#define O_CS    4521985         // new_cluster_size [4096]
#define O_EW    4526081         // new_ema_w    [4096,64] = 262144

// ---- workspace layout (floats) ----
#define W_WSQ    0               // 4096
#define W_CS     4096            // cand scores [2][65536]
#define W_CI     135168          // cand idx    [2][65536] (int)
#define W_CNT    266240          // counts [4096]
#define W_DW     270336          // dw [262144]
#define W_LOSS   532480          // 1
#define W_N      532481          // 1

__global__ void wsq_kernel(const float* __restrict__ w, float* __restrict__ wsq) {
    int k = blockIdx.x * blockDim.x + threadIdx.x;
    if (k >= NUM_K) return;
    const float* wr = w + k * CDIM;
    float s = 0.f;
#pragma unroll
    for (int c = 0; c < CDIM; ++c) { float v = wr[c]; s = fmaf(v, v, s); }
    wsq[k] = s;
}

// Each thread: one input vector, scans 2048 codes (grid.y selects slice).
// Codebook reads are wave-uniform -> scalar loads (s_load) + v_fmac w/ SGPR src.
__global__ void __launch_bounds__(256)
argmin_kernel(const float* __restrict__ x, const float* __restrict__ w,
              const float* __restrict__ wsq,
              float* __restrict__ cand_s, int* __restrict__ cand_i) {
    int n  = blockIdx.x * 256 + threadIdx.x;      // 0..65535
    int b  = n >> 12;                              // / HWDIM
    int hw = n & (HWDIM - 1);
    const float* xp = x + b * CHW + hw;
    float xr[CDIM];
#pragma unroll
    for (int c = 0; c < CDIM; ++c) xr[c] = -2.0f * xp[c * HWDIM];

    int k0 = blockIdx.y * (NUM_K / 2);
    float best = 3.4e38f;
    int bi = k0;
    for (int k = k0; k < k0 + NUM_K / 2; ++k) {
        const float* wr = w + k * CDIM;
        float s0 = wsq[k], s1 = 0.f, s2 = 0.f, s3 = 0.f;
#pragma unroll
        for (int c = 0; c < CDIM; c += 4) {
            s0 = fmaf(xr[c + 0], wr[c + 0], s0);
            s1 = fmaf(xr[c + 1], wr[c + 1], s1);
            s2 = fmaf(xr[c + 2], wr[c + 2], s2);
            s3 = fmaf(xr[c + 3], wr[c + 3], s3);
        }
        float s = (s0 + s1) + (s2 + s3);
        if (s < best) { best = s; bi = k; }   // strict < => first-min like jnp.argmin
    }
    cand_s[blockIdx.y * NVEC + n] = best;
    cand_i[blockIdx.y * NVEC + n] = bi;
}

// Combine slices, gather quantized, STE output, loss partials, histogram + dw scatter.
__global__ void __launch_bounds__(256)
assign_kernel(const float* __restrict__ x, const float* __restrict__ w,
              const float* __restrict__ cand_s, const int* __restrict__ cand_i,
              float* __restrict__ out, float* __restrict__ counts,
              float* __restrict__ dw, float* __restrict__ loss_acc) {
    int n = blockIdx.x * 256 + threadIdx.x;
    float s0 = cand_s[n], s1 = cand_s[NVEC + n];
    int   i0 = cand_i[n], i1 = cand_i[NVEC + n];
    int idx = (s1 < s0) ? i1 : i0;   // tie -> slice 0 (lower k)
    out[O_IDX + n] = (float)idx;
    atomicAdd(&counts[idx], 1.0f);

    int b = n >> 12, hw = n & (HWDIM - 1);
    const float* xp = x + b * CHW + hw;
    const float* wr = w + idx * CDIM;
    float* qp = out + O_Q + b * CHW + hw;
    float lsum = 0.f;
#pragma unroll
    for (int c = 0; c < CDIM; ++c) {
        float xv = xp[c * HWDIM];
        float qv = wr[c];                       // gather; codebook is L2-hot (1 MB)
        qp[c * HWDIM] = xv + (qv - xv);         // STE, matches reference arithmetic
        float d = qv - xv;
        lsum = fmaf(d, d, lsum);
        atomicAdd(&dw[idx * CDIM + c], xv);
    }
    __shared__ float red[256];
    int t = threadIdx.x;
    red[t] = lsum;
    __syncthreads();
    for (int s = 128; s > 0; s >>= 1) {
        if (t < s) red[t] += red[t + s];
        __syncthreads();
    }
    if (t == 0) atomicAdd(loss_acc, red[0]);
}

// Single block: new_cluster_size, n = sum(ncs), final loss.
__global__ void __launch_bounds__(256)
finalize_cs(const float* __restrict__ ecs, const float* __restrict__ counts,
            float* __restrict__ out, const float* __restrict__ loss_acc,
            float* __restrict__ nptr) {
    int t = threadIdx.x;
    float local = 0.f;
    for (int k = t; k < NUM_K; k += 256) {
        float ncs = 0.99f * ecs[k] + 0.01f * counts[k];
        out[O_CS + k] = ncs;
        local += ncs;
    }
    __shared__ float red[256];
    red[t] = local;
    __syncthreads();
    for (int s = 128; s > 0; s >>= 1) {
        if (t < s) red[t] += red[t + s];
        __syncthreads();
    }
    if (t == 0) {
        nptr[0] = red[0];
        out[O_LOSS] = 0.25f * loss_acc[0] / 4194304.0f;
    }
}

// Elementwise over [4096,64]: new_ema_w and new_weight (coalesced).
__global__ void __launch_bounds__(256)
finalize_w(const float* __restrict__ ema_w, const float* __restrict__ dw,
           float* __restrict__ out, const float* __restrict__ nptr) {
    int e = blockIdx.x * 256 + threadIdx.x;   // 0..262143
    int k = e >> 6;                            // wave-uniform (64 lanes share k)
    float n = nptr[0];
    float ncs = out[O_CS + k];
    float cs = (ncs + 1e-5f) / (n + NUM_K * 1e-5f) * n;
    float ew = 0.99f * ema_w[e] + 0.01f * dw[e];
    out[O_EW + e] = ew;
    out[O_W + e] = ew / cs;
}

extern "C" void kernel_launch(void* const* d_in, const int* in_sizes, int n_in,
                              void* d_out, int out_size, void* d_ws, size_t ws_size,
                              hipStream_t stream) {
    const float* x     = (const float*)d_in[0];   // inputs [16,64,64,64]
    const float* w     = (const float*)d_in[1];   // weight [4096,64]
    const float* ecs   = (const float*)d_in[2];   // ema_cluster_size [4096]
    const float* ema_w = (const float*)d_in[3];   // ema_w [4096,64]
    float* out = (float*)d_out;
    float* ws  = (float*)d_ws;

    float* wsq    = ws + W_WSQ;
    float* cand_s = ws + W_CS;
    int*   cand_i = (int*)(ws + W_CI);
    float* counts = ws + W_CNT;
    float* dw     = ws + W_DW;
    float* loss_a = ws + W_LOSS;
    float* nptr   = ws + W_N;

    // zero counts + dw + loss (contiguous region)
    hipMemsetAsync(counts, 0, (size_t)(NUM_K + CHW + 1) * sizeof(float), stream);

    wsq_kernel<<<NUM_K / 256, 256, 0, stream>>>(w, wsq);
    argmin_kernel<<<dim3(NVEC / 256, 2), 256, 0, stream>>>(x, w, wsq, cand_s, cand_i);
    assign_kernel<<<NVEC / 256, 256, 0, stream>>>(x, w, cand_s, cand_i, out, counts, dw, loss_a);
    finalize_cs<<<1, 256, 0, stream>>>(ecs, counts, out, loss_a, nptr);
    finalize_w<<<CHW / 256, 256, 0, stream>>>(ema_w, dw, out, nptr);
}

// Round 2
// 1203.490 us; speedup vs baseline: 1.2409x; 1.2409x over previous
//
#include <hip/hip_runtime.h>

#define NUM_K   4096
#define CDIM    64
#define HWDIM   4096            // 64*64
#define NVEC    65536           // 16 * 64 * 64
#define CHW     (CDIM * HWDIM)  // 262144
#define NSLICE  8
#define KSLICE  (NUM_K / NSLICE)   // 512

// ---- output layout (floats, concatenated in reference return order) ----
#define O_Q     0               // quantized_ste  [16,64,64,64] = 4194304
#define O_LOSS  4194304         // scalar
#define O_IDX   4194305         // encoding_indices [16,64,64] = 65536 (as float)
#define O_W     4259841         // new_weight   [4096,64] = 262144
#define O_CS    4521985         // new_cluster_size [4096]
#define O_EW    4526081         // new_ema_w    [4096,64] = 262144

// ---- workspace layout (floats) ----
#define W_WSQ    0               // 4096
#define W_BEST   4096            // packed u64 best [65536] -> 131072 floats
#define W_CNT    135168          // counts [4096]
#define W_DW     139264          // dw [262144]
#define W_LOSS   401408          // 1
#define W_N      401409          // 1

__device__ __forceinline__ unsigned f2ord(float f) {
    unsigned u = __float_as_uint(f);
    return (u & 0x80000000u) ? ~u : (u | 0x80000000u);  // monotone for all finite floats
}

__global__ void wsq_kernel(const float* __restrict__ w, float* __restrict__ wsq) {
    int k = blockIdx.x * blockDim.x + threadIdx.x;
    if (k >= NUM_K) return;
    const float* wr = w + k * CDIM;
    float s = 0.f;
#pragma unroll
    for (int c = 0; c < CDIM; ++c) { float v = wr[c]; s = fmaf(v, v, s); }
    wsq[k] = s;
}

// One thread = one input vector, scans KSLICE codes (grid.y = slice).
// Codebook rows are wave-uniform -> SGPR s_loads + v_fmac with SGPR src.
// 8 slices -> 2048 blocks -> 8 blocks/CU -> 32 waves/CU to hide s_load latency.
__global__ void __launch_bounds__(256)
argmin_kernel(const float* __restrict__ x, const float* __restrict__ w,
              const float* __restrict__ wsq,
              unsigned long long* __restrict__ best_arr) {
    int n  = blockIdx.x * 256 + threadIdx.x;      // 0..65535
    int b  = n >> 12;                              // / HWDIM
    int hw = n & (HWDIM - 1);
    const float* xp = x + b * CHW + hw;
    float xr[CDIM];
#pragma unroll
    for (int c = 0; c < CDIM; ++c) xr[c] = -2.0f * xp[c * HWDIM];

    int k0 = blockIdx.y * KSLICE;
    float best = 3.4e38f;
    int bi = k0;
    for (int k = k0; k < k0 + KSLICE; ++k) {
        const float* wr = w + k * CDIM;
        float s0 = wsq[k], s1 = 0.f, s2 = 0.f, s3 = 0.f;
#pragma unroll
        for (int c = 0; c < CDIM; c += 4) {
            s0 = fmaf(xr[c + 0], wr[c + 0], s0);
            s1 = fmaf(xr[c + 1], wr[c + 1], s1);
            s2 = fmaf(xr[c + 2], wr[c + 2], s2);
            s3 = fmaf(xr[c + 3], wr[c + 3], s3);
        }
        float s = (s0 + s1) + (s2 + s3);
        if (s < best) { best = s; bi = k; }   // strict < => first-min within slice
    }
    // pack: (order-preserving score << 32) | k. atomicMin picks global min,
    // lower k on exact ties -> matches jnp.argmin first-min semantics.
    unsigned long long key = ((unsigned long long)f2ord(best) << 32) | (unsigned)bi;
    atomicMin(&best_arr[n], key);
}

// Gather quantized, STE output, loss partials, histogram + dw scatter.
__global__ void __launch_bounds__(256)
assign_kernel(const float* __restrict__ x, const float* __restrict__ w,
              const unsigned long long* __restrict__ best_arr,
              float* __restrict__ out, float* __restrict__ counts,
              float* __restrict__ dw, float* __restrict__ loss_acc) {
    int n = blockIdx.x * 256 + threadIdx.x;
    int idx = (int)(best_arr[n] & 0xFFFFFFFFu);
    out[O_IDX + n] = (float)idx;
    atomicAdd(&counts[idx], 1.0f);

    int b = n >> 12, hw = n & (HWDIM - 1);
    const float* xp = x + b * CHW + hw;
    const float* wr = w + idx * CDIM;
    float* qp = out + O_Q + b * CHW + hw;
    float lsum = 0.f;
#pragma unroll
    for (int c = 0; c < CDIM; ++c) {
        float xv = xp[c * HWDIM];
        float qv = wr[c];                       // gather; codebook is L2-hot (1 MB)
        qp[c * HWDIM] = xv + (qv - xv);         // STE, matches reference arithmetic
        float d = qv - xv;
        lsum = fmaf(d, d, lsum);
        atomicAdd(&dw[idx * CDIM + c], xv);
    }
    __shared__ float red[256];
    int t = threadIdx.x;
    red[t] = lsum;
    __syncthreads();
    for (int s = 128; s > 0; s >>= 1) {
        if (t < s) red[t] += red[t + s];
        __syncthreads();
    }
    if (t == 0) atomicAdd(loss_acc, red[0]);
}

// Single block: new_cluster_size, n = sum(ncs), final loss.
__global__ void __launch_bounds__(256)
finalize_cs(const float* __restrict__ ecs, const float* __restrict__ counts,
            float* __restrict__ out, const float* __restrict__ loss_acc,
            float* __restrict__ nptr) {
    int t = threadIdx.x;
    float local = 0.f;
    for (int k = t; k < NUM_K; k += 256) {
        float ncs = 0.99f * ecs[k] + 0.01f * counts[k];
        out[O_CS + k] = ncs;
        local += ncs;
    }
    __shared__ float red[256];
    red[t] = local;
    __syncthreads();
    for (int s = 128; s > 0; s >>= 1) {
        if (t < s) red[t] += red[t + s];
        __syncthreads();
    }
    if (t == 0) {
        nptr[0] = red[0];
        out[O_LOSS] = 0.25f * loss_acc[0] / 4194304.0f;
    }
}

// Elementwise over [4096,64]: new_ema_w and new_weight (coalesced).
__global__ void __launch_bounds__(256)
finalize_w(const float* __restrict__ ema_w, const float* __restrict__ dw,
           float* __restrict__ out, const float* __restrict__ nptr) {
    int e = blockIdx.x * 256 + threadIdx.x;   // 0..262143
    int k = e >> 6;                            // wave-uniform (64 lanes share k)
    float n = nptr[0];
    float ncs = out[O_CS + k];
    float cs = (ncs + 1e-5f) / (n + NUM_K * 1e-5f) * n;
    float ew = 0.99f * ema_w[e] + 0.01f * dw[e];
    out[O_EW + e] = ew;
    out[O_W + e] = ew / cs;
}

extern "C" void kernel_launch(void* const* d_in, const int* in_sizes, int n_in,
                              void* d_out, int out_size, void* d_ws, size_t ws_size,
                              hipStream_t stream) {
    const float* x     = (const float*)d_in[0];   // inputs [16,64,64,64]
    const float* w     = (const float*)d_in[1];   // weight [4096,64]
    const float* ecs   = (const float*)d_in[2];   // ema_cluster_size [4096]
    const float* ema_w = (const float*)d_in[3];   // ema_w [4096,64]
    float* out = (float*)d_out;
    float* ws  = (float*)d_ws;

    float* wsq    = ws + W_WSQ;
    unsigned long long* best_arr = (unsigned long long*)(ws + W_BEST);
    float* counts = ws + W_CNT;
    float* dw     = ws + W_DW;
    float* loss_a = ws + W_LOSS;
    float* nptr   = ws + W_N;

    // best keys -> 0xFF.. (max u64); counts + dw + loss -> 0
    hipMemsetAsync(best_arr, 0xFF, (size_t)NVEC * sizeof(unsigned long long), stream);
    hipMemsetAsync(counts, 0, (size_t)(NUM_K + CHW + 1) * sizeof(float), stream);

    wsq_kernel<<<NUM_K / 256, 256, 0, stream>>>(w, wsq);
    argmin_kernel<<<dim3(NVEC / 256, NSLICE), 256, 0, stream>>>(x, w, wsq, best_arr);
    assign_kernel<<<NVEC / 256, 256, 0, stream>>>(x, w, best_arr, out, counts, dw, loss_a);
    finalize_cs<<<1, 256, 0, stream>>>(ecs, counts, out, loss_a, nptr);
    finalize_w<<<CHW / 256, 256, 0, stream>>>(ema_w, dw, out, nptr);
}

// Round 3
// 516.585 us; speedup vs baseline: 2.8909x; 2.3297x over previous
//
#include <hip/hip_runtime.h>

#define NUM_K   4096
#define CDIM    64
#define HWDIM   4096            // 64*64
#define NVEC    65536           // 16 * 64 * 64
#define CHW     (CDIM * HWDIM)  // 262144
#define NSLICE  16
#define KSLICE  (NUM_K / NSLICE)   // 256

// ---- output layout (floats, concatenated in reference return order) ----
#define O_Q     0               // quantized_ste  [16,64,64,64] = 4194304
#define O_LOSS  4194304         // scalar
#define O_IDX   4194305         // encoding_indices [16,64,64] = 65536 (as float)
#define O_W     4259841         // new_weight   [4096,64] = 262144
#define O_CS    4521985         // new_cluster_size [4096]
#define O_EW    4526081         // new_ema_w    [4096,64] = 262144

// ---- workspace layout (floats) ----
#define W_WSQ    0               // 4096
#define W_BEST   4096            // packed u64 best [65536] -> 131072 floats
#define W_CNT    135168          // counts [4096]
#define W_DW     139264          // dw [262144]
#define W_LOSS   401408          // 1
#define W_N      401409          // 1

typedef unsigned long long u64;

__device__ __forceinline__ unsigned f2ord(float f) {
    unsigned u = __float_as_uint(f);
    return (u & 0x80000000u) ? ~u : (u | 0x80000000u);  // monotone for all finite floats
}

__global__ void wsq_kernel(const float* __restrict__ w, float* __restrict__ wsq) {
    int k = blockIdx.x * blockDim.x + threadIdx.x;
    if (k >= NUM_K) return;
    const float* wr = w + k * CDIM;
    float s = 0.f;
#pragma unroll
    for (int c = 0; c < CDIM; ++c) { float v = wr[c]; s = fmaf(v, v, s); }
    wsq[k] = s;
}

// One thread = TWO input vectors (n, n+32768), scans KSLICE codes (grid.y = slice).
// Codebook rows are wave-uniform -> SGPR s_loads; 2 vectors double the FMA work
// per 256B row fetch, so the VALU issue port saturates even at ~3 waves/SIMD.
__global__ void __launch_bounds__(256)
argmin_kernel(const float* __restrict__ x, const float* __restrict__ w,
              const float* __restrict__ wsq,
              u64* __restrict__ best_arr) {
    int t = threadIdx.x;
    int n  = blockIdx.x * 256 + t;       // 0..32767
    int n2 = n + NVEC / 2;
    int b  = n  >> 12, hw  = n  & (HWDIM - 1);
    int b2 = n2 >> 12, hw2 = n2 & (HWDIM - 1);
    const float* xp  = x + b  * CHW + hw;
    const float* xp2 = x + b2 * CHW + hw2;
    float xa[CDIM], xb[CDIM];
#pragma unroll
    for (int c = 0; c < CDIM; ++c) xa[c] = -2.0f * xp [c * HWDIM];
#pragma unroll
    for (int c = 0; c < CDIM; ++c) xb[c] = -2.0f * xp2[c * HWDIM];

    int k0 = blockIdx.y * KSLICE;
    float bestA = 3.4e38f, bestB = 3.4e38f;
    int ia = k0, ib = k0;
    for (int k = k0; k < k0 + KSLICE; ++k) {
        const float* wr = w + k * CDIM;
        float a0 = wsq[k], a1 = 0.f, a2 = 0.f, a3 = 0.f;
        float b0 = a0,     b1 = 0.f, b2 = 0.f, b3 = 0.f;
#pragma unroll
        for (int c = 0; c < CDIM; c += 4) {
            float w0 = wr[c], w1 = wr[c + 1], w2 = wr[c + 2], w3 = wr[c + 3];
            a0 = fmaf(xa[c + 0], w0, a0);
            a1 = fmaf(xa[c + 1], w1, a1);
            a2 = fmaf(xa[c + 2], w2, a2);
            a3 = fmaf(xa[c + 3], w3, a3);
            b0 = fmaf(xb[c + 0], w0, b0);
            b1 = fmaf(xb[c + 1], w1, b1);
            b2 = fmaf(xb[c + 2], w2, b2);
            b3 = fmaf(xb[c + 3], w3, b3);
        }
        float sa = (a0 + a1) + (a2 + a3);
        float sb = (b0 + b1) + (b2 + b3);
        if (sa < bestA) { bestA = sa; ia = k; }   // strict < => first-min within slice
        if (sb < bestB) { bestB = sb; ib = k; }
    }
    // (order-preserving score << 32) | k; atomicMin => global min, lower k on ties.
    atomicMin(&best_arr[n],  ((u64)f2ord(bestA) << 32) | (unsigned)ia);
    atomicMin(&best_arr[n2], ((u64)f2ord(bestB) << 32) | (unsigned)ib);
}

// Block = 64 vectors. x staged transposed in LDS once; quantized/STE/loss from LDS;
// dw scatter as wave-coalesced row atomics (idx wave-uniform, lane = c).
__global__ void __launch_bounds__(256)
assign_kernel(const float* __restrict__ x, const float* __restrict__ w,
              const u64* __restrict__ best_arr,
              float* __restrict__ out, float* __restrict__ counts,
              float* __restrict__ dw, float* __restrict__ loss_acc) {
    __shared__ float xs[64][CDIM + 1];   // 16.6 KB, padded
    __shared__ int   sidx[64];
    __shared__ float red[256];

    int t  = threadIdx.x;
    int n0 = blockIdx.x * 64;
    int b  = n0 >> 12;                    // constant across the block (64 | 4096)
    int hw0 = n0 & (HWDIM - 1);
    const float* xbase = x + b * CHW + hw0;

    if (t < 64) {
        int idx = (int)(best_arr[n0 + t] & 0xFFFFFFFFu);
        sidx[t] = idx;
        out[O_IDX + n0 + t] = (float)idx;
        atomicAdd(&counts[idx], 1.0f);
    }

    int lane = t & 63, wv = t >> 6;       // wave wv handles c = wv + 4j
    // stage x -> LDS transposed; each wave reads 64 consecutive floats per c (coalesced)
#pragma unroll
    for (int j = 0; j < 16; ++j) {
        int c = wv + j * 4;
        xs[lane][c] = xbase[c * HWDIM + lane];
    }
    __syncthreads();

    // quantized_ste + loss partials; per (c) the 64 lanes write consecutive addrs
    float lsum = 0.f;
#pragma unroll
    for (int j = 0; j < 16; ++j) {
        int c = wv + j * 4;
        float xv = xs[lane][c];
        float qv = w[sidx[lane] * CDIM + c];    // gather; codebook L2-hot (1 MB)
        float d = qv - xv;
        out[O_Q + b * CHW + c * HWDIM + hw0 + lane] = xv + d;  // STE arithmetic as ref
        lsum = fmaf(d, d, lsum);
    }
    red[t] = lsum;
    __syncthreads();
    for (int s = 128; s > 0; s >>= 1) {
        if (t < s) red[t] += red[t + s];
        __syncthreads();
    }
    if (t == 0) atomicAdd(loss_acc, red[0]);

    // dw scatter: wave-uniform idx, lanes cover the 64 channels -> coalesced atomic rows
    for (int i = 0; i < 16; ++i) {
        int nl = wv * 16 + i;
        atomicAdd(&dw[sidx[nl] * CDIM + lane], xs[nl][lane]);
    }
}

// Single block: new_cluster_size, n = sum(ncs), final loss.
__global__ void __launch_bounds__(256)
finalize_cs(const float* __restrict__ ecs, const float* __restrict__ counts,
            float* __restrict__ out, const float* __restrict__ loss_acc,
            float* __restrict__ nptr) {
    int t = threadIdx.x;
    float local = 0.f;
    for (int k = t; k < NUM_K; k += 256) {
        float ncs = 0.99f * ecs[k] + 0.01f * counts[k];
        out[O_CS + k] = ncs;
        local += ncs;
    }
    __shared__ float red[256];
    red[t] = local;
    __syncthreads();
    for (int s = 128; s > 0; s >>= 1) {
        if (t < s) red[t] += red[t + s];
        __syncthreads();
    }
    if (t == 0) {
        nptr[0] = red[0];
        out[O_LOSS] = 0.25f * loss_acc[0] / 4194304.0f;
    }
}

// Elementwise over [4096,64]: new_ema_w and new_weight (coalesced).
__global__ void __launch_bounds__(256)
finalize_w(const float* __restrict__ ema_w, const float* __restrict__ dw,
           float* __restrict__ out, const float* __restrict__ nptr) {
    int e = blockIdx.x * 256 + threadIdx.x;   // 0..262143
    int k = e >> 6;                            // wave-uniform (64 lanes share k)
    float n = nptr[0];
    float ncs = out[O_CS + k];
    float cs = (ncs + 1e-5f) / (n + NUM_K * 1e-5f) * n;
    float ew = 0.99f * ema_w[e] + 0.01f * dw[e];
    out[O_EW + e] = ew;
    out[O_W + e] = ew / cs;
}

extern "C" void kernel_launch(void* const* d_in, const int* in_sizes, int n_in,
                              void* d_out, int out_size, void* d_ws, size_t ws_size,
                              hipStream_t stream) {
    const float* x     = (const float*)d_in[0];   // inputs [16,64,64,64]
    const float* w     = (const float*)d_in[1];   // weight [4096,64]
    const float* ecs   = (const float*)d_in[2];   // ema_cluster_size [4096]
    const float* ema_w = (const float*)d_in[3];   // ema_w [4096,64]
    float* out = (float*)d_out;
    float* ws  = (float*)d_ws;

    float* wsq    = ws + W_WSQ;
    u64*   best_arr = (u64*)(ws + W_BEST);
    float* counts = ws + W_CNT;
    float* dw     = ws + W_DW;
    float* loss_a = ws + W_LOSS;
    float* nptr   = ws + W_N;

    // best keys -> 0xFF.. (max u64); counts + dw + loss -> 0
    hipMemsetAsync(best_arr, 0xFF, (size_t)NVEC * sizeof(u64), stream);
    hipMemsetAsync(counts, 0, (size_t)(NUM_K + CHW + 1) * sizeof(float), stream);

    wsq_kernel<<<NUM_K / 256, 256, 0, stream>>>(w, wsq);
    argmin_kernel<<<dim3(NVEC / 2 / 256, NSLICE), 256, 0, stream>>>(x, w, wsq, best_arr);
    assign_kernel<<<NVEC / 64, 256, 0, stream>>>(x, w, best_arr, out, counts, dw, loss_a);
    finalize_cs<<<1, 256, 0, stream>>>(ecs, counts, out, loss_a, nptr);
    finalize_w<<<CHW / 256, 256, 0, stream>>>(ema_w, dw, out, nptr);
}